// Round 1
// baseline (610.240 us; speedup 1.0000x reference)
//
#include <hip/hip_runtime.h>

#define DD 1024
#define FF 4096
#define LL 24
#define VV 50277

// ---------------- reduction helpers ----------------

__device__ __forceinline__ float wave_sum(float v) {
#pragma unroll
    for (int o = 32; o > 0; o >>= 1) v += __shfl_xor(v, o, 64);
    return v;
}

// block(256)-wide sum with broadcast; scr is 4-float LDS scratch
__device__ __forceinline__ float block_sum(float v, float* scr) {
    v = wave_sum(v);
    int w = threadIdx.x >> 6;
    __syncthreads();                       // protect scr from previous use
    if ((threadIdx.x & 63) == 0) scr[w] = v;
    __syncthreads();
    return scr[0] + scr[1] + scr[2] + scr[3];
}

// LayerNorm over D=1024: thread t owns dims [4t..4t+3]; returns normalized vals
__device__ __forceinline__ float4 ln_vec(float4 xv, const float* __restrict__ w,
                                         const float* __restrict__ b,
                                         float* scr, int t) {
    float s = xv.x + xv.y + xv.z + xv.w;
    float m = block_sum(s, scr) * (1.0f / (float)DD);
    float dx = xv.x - m, dy = xv.y - m, dz = xv.z - m, dw = xv.w - m;
    float var = block_sum(dx * dx + dy * dy + dz * dz + dw * dw, scr) * (1.0f / (float)DD);
    float rs = rsqrtf(var + 1e-5f);
    float4 w4 = ((const float4*)w)[t];
    float4 b4 = ((const float4*)b)[t];
    return make_float4(dx * rs * w4.x + b4.x, dy * rs * w4.y + b4.y,
                       dz * rs * w4.z + b4.z, dw * rs * w4.w + b4.w);
}

// ---------------- K0: standalone LayerNorm (encoder & pre-head) ----------------

__global__ __launch_bounds__(256) void k_ln(const float* __restrict__ xin,
                                            const float* __restrict__ w,
                                            const float* __restrict__ b,
                                            float* __restrict__ xout) {
    __shared__ float scr[4];
    int t = threadIdx.x;
    float4 v = ((const float4*)xin)[t];
    float4 n = ln_vec(v, w, b, scr, t);
    ((float4*)xout)[t] = n;
}

// ---------------- K1: LN1 + time-mix + {kw,vw,rw} GEMV ----------------
// grid = 768 blocks, 4 waves/block, 1 row/wave over 3072 combined rows

__global__ __launch_bounds__(256) void k1_timemix(
    const float* __restrict__ x, const float* __restrict__ st,
    const float* __restrict__ l1w, const float* __restrict__ l1b,
    const float* __restrict__ tmk, const float* __restrict__ tmv,
    const float* __restrict__ tmr,
    const float* __restrict__ kw, const float* __restrict__ vw,
    const float* __restrict__ rw,
    float* __restrict__ kk, float* __restrict__ vv, float* __restrict__ rr,
    float* __restrict__ st_out) {
    __shared__ __align__(16) float xk[DD];
    __shared__ __align__(16) float xv_[DD];
    __shared__ __align__(16) float xr[DD];
    __shared__ float scr[4];
    int t = threadIdx.x;

    float4 xvec = ((const float4*)x)[t];
    float4 n = ln_vec(xvec, l1w, l1b, scr, t);
    if (blockIdx.x == 0) ((float4*)(st_out + DD))[t] = n;  // new_st[1] = xn

    float4 sa = ((const float4*)(st + DD))[t];  // s_att = old st[1]
    float4 mk = ((const float4*)tmk)[t];
    float4 mv = ((const float4*)tmv)[t];
    float4 mr = ((const float4*)tmr)[t];
    ((float4*)xk)[t] = make_float4(n.x * mk.x + sa.x * (1.f - mk.x),
                                   n.y * mk.y + sa.y * (1.f - mk.y),
                                   n.z * mk.z + sa.z * (1.f - mk.z),
                                   n.w * mk.w + sa.w * (1.f - mk.w));
    ((float4*)xv_)[t] = make_float4(n.x * mv.x + sa.x * (1.f - mv.x),
                                    n.y * mv.y + sa.y * (1.f - mv.y),
                                    n.z * mv.z + sa.z * (1.f - mv.z),
                                    n.w * mv.w + sa.w * (1.f - mv.w));
    ((float4*)xr)[t] = make_float4(n.x * mr.x + sa.x * (1.f - mr.x),
                                   n.y * mr.y + sa.y * (1.f - mr.y),
                                   n.z * mr.z + sa.z * (1.f - mr.z),
                                   n.w * mr.w + sa.w * (1.f - mr.w));
    __syncthreads();

    int lane = t & 63, w = t >> 6;
    int ridx = blockIdx.x * 4 + w;      // [0,3072)
    int m = ridx >> 10, row = ridx & 1023;
    const float* W = (m == 0 ? kw : (m == 1 ? vw : rw)) + (size_t)row * DD;
    const float* vec = (m == 0 ? xk : (m == 1 ? xv_ : xr));
    const float4* W4 = (const float4*)W;
    const float4* v4 = (const float4*)vec;
    float acc = 0.f;
#pragma unroll
    for (int j = 0; j < 4; ++j) {
        float4 a = W4[lane + 64 * j];
        float4 bx = v4[lane + 64 * j];
        acc = fmaf(a.x, bx.x, fmaf(a.y, bx.y, fmaf(a.z, bx.z, fmaf(a.w, bx.w, acc))));
    }
    acc = wave_sum(acc);
    if (lane == 0) {
        if (m == 0) kk[row] = acc;
        else if (m == 1) vv[row] = acc;
        else rr[row] = 1.0f / (1.0f + expf(-acc));   // r = sigmoid(rw@xr)
    }
}

// ---------------- K2: wkv elementwise + state write + ow GEMV + residual ----------------
// grid = 256 blocks

__global__ __launch_bounds__(256) void k2_wkv_out(
    const float* __restrict__ st,
    const float* __restrict__ tf, const float* __restrict__ td,
    const float* __restrict__ kk, const float* __restrict__ vv,
    const float* __restrict__ rr, const float* __restrict__ ow,
    float* __restrict__ x, float* __restrict__ st_out) {
    __shared__ __align__(16) float rab[DD];
    int t = threadIdx.x;

    float4 kk4 = ((const float4*)kk)[t];
    float4 vv4 = ((const float4*)vv)[t];
    float4 r4  = ((const float4*)rr)[t];
    float4 aa4 = ((const float4*)(st + 2 * DD))[t];
    float4 bb4 = ((const float4*)(st + 3 * DD))[t];
    float4 pp4 = ((const float4*)(st + 4 * DD))[t];
    float4 tf4 = ((const float4*)tf)[t];
    float4 td4 = ((const float4*)td)[t];
    float4 rabv, naa, nbb, np2;
    const float* kkp = (const float*)&kk4; const float* vvp = (const float*)&vv4;
    const float* rp = (const float*)&r4;   const float* aap = (const float*)&aa4;
    const float* bbp = (const float*)&bb4; const float* ppp = (const float*)&pp4;
    const float* tfp = (const float*)&tf4; const float* tdp = (const float*)&td4;
#pragma unroll
    for (int c = 0; c < 4; ++c) {
        float kx = kkp[c], vx = vvp[c], rx = rp[c];
        float ax = aap[c], bx = bbp[c], px = ppp[c];
        float ww = tfp[c] + kx;
        float p = fmaxf(px, ww);
        float e1 = expf(px - p), e2 = expf(ww - p);
        float a = e1 * ax + e2 * vx;
        float b = e1 * bx + e2;
        ((float*)&rabv)[c] = rx * (a / b);
        float ww2 = px + tdp[c];
        float p2 = fmaxf(ww2, kx);
        float f1 = expf(ww2 - p2), f2 = expf(kx - p2);
        ((float*)&naa)[c] = f1 * ax + f2 * vx;
        ((float*)&nbb)[c] = f1 * bx + f2;
        ((float*)&np2)[c] = p2;
    }
    ((float4*)rab)[t] = rabv;
    if (blockIdx.x == 0) {
        ((float4*)(st_out + 2 * DD))[t] = naa;
        ((float4*)(st_out + 3 * DD))[t] = nbb;
        ((float4*)(st_out + 4 * DD))[t] = np2;
    }
    __syncthreads();

    int lane = t & 63, w = t >> 6;
    int row = blockIdx.x * 4 + w;
    const float4* W4 = (const float4*)(ow + (size_t)row * DD);
    const float4* v4 = (const float4*)rab;
    float acc = 0.f;
#pragma unroll
    for (int j = 0; j < 4; ++j) {
        float4 a = W4[lane + 64 * j];
        float4 bx = v4[lane + 64 * j];
        acc = fmaf(a.x, bx.x, fmaf(a.y, bx.y, fmaf(a.z, bx.z, fmaf(a.w, bx.w, acc))));
    }
    acc = wave_sum(acc);
    if (lane == 0) x[row] += acc;   // residual
}

// ---------------- K3: LN2 + chan-mix + {fkw,frw} GEMV (relu^2 / sigmoid fused) ----------------
// grid = 1280 blocks over 5120 combined rows

__global__ __launch_bounds__(256) void k3_ffn_kr(
    const float* __restrict__ x, const float* __restrict__ st,
    const float* __restrict__ l2w, const float* __restrict__ l2b,
    const float* __restrict__ ftmk, const float* __restrict__ ftmr,
    const float* __restrict__ fkw, const float* __restrict__ frw,
    float* __restrict__ k2, float* __restrict__ r2, float* __restrict__ st_out) {
    __shared__ __align__(16) float xk2[DD];
    __shared__ __align__(16) float xr2[DD];
    __shared__ float scr[4];
    int t = threadIdx.x;

    float4 xvec = ((const float4*)x)[t];
    float4 n = ln_vec(xvec, l2w, l2b, scr, t);
    if (blockIdx.x == 0) ((float4*)st_out)[t] = n;  // new_st[0] = xn2

    float4 sf = ((const float4*)st)[t];             // s_ffn = old st[0]
    float4 mk = ((const float4*)ftmk)[t];
    float4 mr = ((const float4*)ftmr)[t];
    ((float4*)xk2)[t] = make_float4(n.x * mk.x + sf.x * (1.f - mk.x),
                                    n.y * mk.y + sf.y * (1.f - mk.y),
                                    n.z * mk.z + sf.z * (1.f - mk.z),
                                    n.w * mk.w + sf.w * (1.f - mk.w));
    ((float4*)xr2)[t] = make_float4(n.x * mr.x + sf.x * (1.f - mr.x),
                                    n.y * mr.y + sf.y * (1.f - mr.y),
                                    n.z * mr.z + sf.z * (1.f - mr.z),
                                    n.w * mr.w + sf.w * (1.f - mr.w));
    __syncthreads();

    int lane = t & 63, w = t >> 6;
    int ridx = blockIdx.x * 4 + w;   // [0,5120)
    const float* W;
    const float* vec;
    if (ridx < FF) { W = fkw + (size_t)ridx * DD; vec = xk2; }
    else           { W = frw + (size_t)(ridx - FF) * DD; vec = xr2; }
    const float4* W4 = (const float4*)W;
    const float4* v4 = (const float4*)vec;
    float acc = 0.f;
#pragma unroll
    for (int j = 0; j < 4; ++j) {
        float4 a = W4[lane + 64 * j];
        float4 bx = v4[lane + 64 * j];
        acc = fmaf(a.x, bx.x, fmaf(a.y, bx.y, fmaf(a.z, bx.z, fmaf(a.w, bx.w, acc))));
    }
    acc = wave_sum(acc);
    if (lane == 0) {
        if (ridx < FF) {
            float rl = fmaxf(acc, 0.f);
            k2[ridx] = rl * rl;                       // square(relu(.))
        } else {
            r2[ridx - FF] = 1.0f / (1.0f + expf(-acc)); // sigmoid
        }
    }
}

// ---------------- K4: fvw GEMV + gated residual + rescale ----------------
// grid = 256 blocks

__global__ __launch_bounds__(256) void k4_ffn_v(
    const float* __restrict__ fvw, const float* __restrict__ k2,
    const float* __restrict__ r2, float* __restrict__ x, float scale) {
    __shared__ __align__(16) float k2s[FF];
    int t = threadIdx.x;
#pragma unroll
    for (int j = 0; j < 4; ++j)
        ((float4*)k2s)[t + 256 * j] = ((const float4*)k2)[t + 256 * j];
    __syncthreads();

    int lane = t & 63, w = t >> 6;
    int row = blockIdx.x * 4 + w;
    const float4* W4 = (const float4*)(fvw + (size_t)row * FF);
    const float4* v4 = (const float4*)k2s;
    float acc = 0.f;
#pragma unroll
    for (int j = 0; j < 16; ++j) {
        float4 a = W4[lane + 64 * j];
        float4 bx = v4[lane + 64 * j];
        acc = fmaf(a.x, bx.x, fmaf(a.y, bx.y, fmaf(a.z, bx.z, fmaf(a.w, bx.w, acc))));
    }
    acc = wave_sum(acc);
    if (lane == 0) x[row] = (x[row] + r2[row] * acc) * scale;
}

// ---------------- head: 50277x1024 GEMV ----------------

__global__ __launch_bounds__(256) void k_head(const float* __restrict__ head_w,
                                              const float* __restrict__ xn,
                                              float* __restrict__ logits) {
    __shared__ __align__(16) float xs[DD];
    int t = threadIdx.x;
    ((float4*)xs)[t] = ((const float4*)xn)[t];
    __syncthreads();

    int lane = t & 63, w = t >> 6;
    int row = blockIdx.x * 4 + w;
    if (row >= VV) return;
    const float4* W4 = (const float4*)(head_w + (size_t)row * DD);
    const float4* v4 = (const float4*)xs;
    float acc = 0.f;
#pragma unroll
    for (int j = 0; j < 4; ++j) {
        float4 a = W4[lane + 64 * j];
        float4 bx = v4[lane + 64 * j];
        acc = fmaf(a.x, bx.x, fmaf(a.y, bx.y, fmaf(a.z, bx.z, fmaf(a.w, bx.w, acc))));
    }
    acc = wave_sum(acc);
    if (lane == 0) logits[row] = acc;
}

// ---------------- launch ----------------

extern "C" void kernel_launch(void* const* d_in, const int* in_sizes, int n_in,
                              void* d_out, int out_size, void* d_ws, size_t ws_size,
                              hipStream_t stream) {
    const float* token_embd = (const float*)d_in[0];
    const float* state      = (const float*)d_in[1];
    const float* emb_ln_w   = (const float*)d_in[2];
    const float* emb_ln_b   = (const float*)d_in[3];
    const float* ln1_w      = (const float*)d_in[4];
    const float* ln1_b      = (const float*)d_in[5];
    const float* ln2_w      = (const float*)d_in[6];
    const float* ln2_b      = (const float*)d_in[7];
    const float* att_tmk    = (const float*)d_in[8];
    const float* att_tmv    = (const float*)d_in[9];
    const float* att_tmr    = (const float*)d_in[10];
    const float* att_tf     = (const float*)d_in[11];
    const float* att_td     = (const float*)d_in[12];
    const float* att_kw     = (const float*)d_in[13];
    const float* att_vw     = (const float*)d_in[14];
    const float* att_rw     = (const float*)d_in[15];
    const float* att_ow     = (const float*)d_in[16];
    const float* ffn_tmk    = (const float*)d_in[17];
    const float* ffn_tmr    = (const float*)d_in[18];
    const float* ffn_kw     = (const float*)d_in[19];
    const float* ffn_vw     = (const float*)d_in[20];
    const float* ffn_rw     = (const float*)d_in[21];
    const float* out_ln_w   = (const float*)d_in[22];
    const float* out_ln_b   = (const float*)d_in[23];
    const float* head_w     = (const float*)d_in[24];

    float* logits = (float*)d_out;
    float* st_out_base = (float*)d_out + VV;

    float* ws  = (float*)d_ws;
    float* x   = ws;               // 1024
    float* kk  = ws + 1024;        // 1024
    float* vv  = ws + 2048;        // 1024
    float* rr  = ws + 3072;        // 1024
    float* k2  = ws + 4096;        // 4096
    float* r2  = ws + 8192;        // 1024
    float* xnH = ws + 9216;        // 1024

    // encoder: x = LN(token_embd)
    k_ln<<<1, 256, 0, stream>>>(token_embd, emb_ln_w, emb_ln_b, x);

    for (int i = 0; i < LL; ++i) {
        const float* st = state + (size_t)i * 5 * DD;
        float* sto = st_out_base + (size_t)i * 5 * DD;
        k1_timemix<<<768, 256, 0, stream>>>(
            x, st, ln1_w + i * DD, ln1_b + i * DD,
            att_tmk + i * DD, att_tmv + i * DD, att_tmr + i * DD,
            att_kw + (size_t)i * DD * DD, att_vw + (size_t)i * DD * DD,
            att_rw + (size_t)i * DD * DD, kk, vv, rr, sto);
        k2_wkv_out<<<256, 256, 0, stream>>>(
            st, att_tf + i * DD, att_td + i * DD, kk, vv, rr,
            att_ow + (size_t)i * DD * DD, x, sto);
        k3_ffn_kr<<<1280, 256, 0, stream>>>(
            x, st, ln2_w + i * DD, ln2_b + i * DD,
            ffn_tmk + i * DD, ffn_tmr + i * DD,
            ffn_kw + (size_t)i * FF * DD, ffn_rw + (size_t)i * DD * DD,
            k2, r2, sto);
        float scale = ((i + 1) % 6 == 0) ? 0.5f : 1.0f;
        k4_ffn_v<<<256, 256, 0, stream>>>(
            ffn_vw + (size_t)i * DD * FF, k2, r2, x, scale);
    }

    // decoder
    k_ln<<<1, 256, 0, stream>>>(x, out_ln_w, out_ln_b, xnH);
    k_head<<<(VV + 3) / 4, 256, 0, stream>>>(head_w, xnH, logits);
}